// Round 11
// baseline (307.054 us; speedup 1.0000x reference)
//
#include <hip/hip_runtime.h>

#define Bn 4096
#define Tn 200
#define Fn 64
#define Hn 8
#define Gn 24   // 3*H
#define TC 8    // timesteps per chunk (25*8 = 200, no tail)
#define NCH 25

typedef __attribute__((ext_vector_type(8))) short short8;
typedef __attribute__((ext_vector_type(4))) float f32x4;

// ---------- helpers ----------
__device__ __forceinline__ unsigned short bf16_rne(float f) {
  unsigned u = __float_as_uint(f);
  return (unsigned short)((u + 0x7FFFu + ((u >> 16) & 1u)) >> 16);
}
__device__ __forceinline__ float bf16_to_f(unsigned short s) {
  return __uint_as_float(((unsigned)s) << 16);
}
__device__ __forceinline__ float frcp(float x) {
#if __has_builtin(__builtin_amdgcn_rcpf)
  return __builtin_amdgcn_rcpf(x);
#else
  return 1.0f / x;
#endif
}
// Pade [7/6] tanh (continued-fraction truncation), clamp +-4.4, max err ~7e-4.
// FMA/rcp only -- removes exp from the recurrence critical path.
__device__ __forceinline__ float pade_tanh(float y) {
  y = fminf(4.4f, fmaxf(-4.4f, y));
  float u = y * y;
  float num = y * fmaf(u, fmaf(21.0f, u, 1260.0f), 10395.0f);
  float den = fmaf(u, fmaf(u, u + 210.0f, 4725.0f), 10395.0f);
  return num * frcp(den);
}
// cross-lane, all DPP: xor1, xor2 quad_perm; xor7 row_half_mirror (R7-audited)
__device__ __forceinline__ float xf1(float v) {
  return __int_as_float(__builtin_amdgcn_mov_dpp(__float_as_int(v), 0xB1, 0xF, 0xF, true));
}
__device__ __forceinline__ float xf2(float v) {
  return __int_as_float(__builtin_amdgcn_mov_dpp(__float_as_int(v), 0x4E, 0xF, 0xF, true));
}
__device__ __forceinline__ float xf7(float v) {
  return __int_as_float(__builtin_amdgcn_mov_dpp(__float_as_int(v), 0x141, 0xF, 0xF, true));
}
__device__ __forceinline__ unsigned cvt_pk_bf16(float a, float b) {
  unsigned r;
  asm volatile("v_cvt_pk_bf16_f32 %0, %1, %2" : "=v"(r) : "v"(a), "v"(b));
  return r;
}
// trunc-split: hi = bit-truncated bf16 (exact), lo = RNE(residual)  [R9-validated]
__device__ __forceinline__ void split8(const float4& A, const float4& B,
                                       short8& hi, short8& lo) {
  float v[8] = {A.x, A.y, A.z, A.w, B.x, B.y, B.z, B.w};
  union { unsigned u[4]; short8 s; } H, L;
  #pragma unroll
  for (int p = 0; p < 4; ++p) {
    unsigned u0 = __float_as_uint(v[2 * p]), u1 = __float_as_uint(v[2 * p + 1]);
    float h0 = __uint_as_float(u0 & 0xFFFF0000u);
    float h1 = __uint_as_float(u1 & 0xFFFF0000u);
    H.u[p] = (u0 >> 16) | (u1 & 0xFFFF0000u);
    L.u[p] = cvt_pk_bf16(v[2 * p] - h0, v[2 * p + 1] - h1);
  }
  hi = H.s; lo = L.s;
}

// ---------- fused GRU, reg-staged x, Pade activations ----------
// r,z gates computed at HALF scale (weights/biases pre-scaled by 0.5, exact):
//   sigma(y) = 0.5 + 0.5*T(y/2), T = pade_tanh.  n-gate: tanh direct.
__global__ __launch_bounds__(64) void k_fused(
    const float* __restrict__ x, const float* __restrict__ w_ih,
    const float* __restrict__ w_hh, const float* __restrict__ b_ih,
    const float* __restrict__ b_hh, const float* __restrict__ w_dec,
    const float* __restrict__ b_dec, float* __restrict__ out) {
  __shared__ __align__(16) float pbuf[2][TC][8][Gn];  // 12288 B

  const int lane = threadIdx.x & 63;
  const int j  = lane & 7;
  const int bl = lane >> 3;
  const int lm = lane & 15;
  const int lh = lane >> 4;
  const int b0 = blockIdx.x * 8;

  // ---- B fragments of w_ih (hi/lo RNE); r,z rows (g<16) pre-scaled 0.5 ----
  short8 Bh[2][2], Bl[2][2];
  float bias[2];
  #pragma unroll
  for (int nt = 0; nt < 2; ++nt) {
    int gg0 = nt * 16 + lm;
    bool valid = (gg0 < Gn);
    int gg = valid ? gg0 : 0;
    float bsc = (nt == 0) ? 0.5f : 1.0f;
    bias[nt] = valid ? b_ih[gg] * bsc : 0.0f;
    #pragma unroll
    for (int kt = 0; kt < 2; ++kt) {
      const float* wp = w_ih + gg * Fn + kt * 32 + lh * 8;
      #pragma unroll
      for (int q = 0; q < 8; ++q) {
        float v = valid ? wp[q] * bsc : 0.0f;
        unsigned short hh = bf16_rne(v);
        Bh[nt][kt][q] = (short)hh;
        Bl[nt][kt][q] = (short)bf16_rne(v - bf16_to_f(hh));
      }
    }
  }

  // ---- recurrent weights, butterfly-permuted; r,z rows pre-scaled 0.5 ----
  float whr[8], whz[8], whn[8];
  #pragma unroll
  for (int k = 0; k < 8; ++k) {
    int col = j ^ k;
    whr[k] = w_hh[j * 8 + col] * 0.5f;
    whz[k] = w_hh[(8 + j) * 8 + col] * 0.5f;
    whn[k] = w_hh[(16 + j) * 8 + col];
  }
  const float bhr = b_hh[j] * 0.5f, bhz = b_hh[8 + j] * 0.5f, bhn = b_hh[16 + j];
  float wd[8];
  #pragma unroll
  for (int k = 0; k < 8; ++k) wd[k] = w_dec[k];
  const float bd = b_dec[0];

  // ---- per-lane global A-fragment base pointers (one per b-pair) ----
  const float* xb = x + (size_t)b0 * Tn * Fn;
  const float* abase[4];
  #pragma unroll
  for (int bp = 0; bp < 4; ++bp)
    abase[bp] = xb + ((size_t)(bp * 2 + (lm >> 3)) * Tn + (lm & 7)) * Fn + lh * 8;

  float4 ld[4][4];  // chunk staging regs
  auto load_chunk = [&](int c) {
    const int co = c * (TC * Fn);
    #pragma unroll
    for (int bp = 0; bp < 4; ++bp) {
      ld[bp][0] = *(const float4*)(abase[bp] + co);
      ld[bp][1] = *(const float4*)(abase[bp] + co + 4);
      ld[bp][2] = *(const float4*)(abase[bp] + co + 32);
      ld[bp][3] = *(const float4*)(abase[bp] + co + 36);
    }
  };

  // proj current ld -> pbuf[psel]  (split + 12 MFMA per bp + C-write, R6 layout)
  auto proj = [&](int psel) {
    #pragma unroll
    for (int bp = 0; bp < 4; ++bp) {
      short8 Ah0, Al0, Ah1, Al1;
      split8(ld[bp][0], ld[bp][1], Ah0, Al0);
      split8(ld[bp][2], ld[bp][3], Ah1, Al1);
      f32x4 c0 = {0.f, 0.f, 0.f, 0.f}, c1 = {0.f, 0.f, 0.f, 0.f};
      c0 = __builtin_amdgcn_mfma_f32_16x16x32_bf16(Ah0, Bh[0][0], c0, 0, 0, 0);
      c0 = __builtin_amdgcn_mfma_f32_16x16x32_bf16(Ah0, Bl[0][0], c0, 0, 0, 0);
      c0 = __builtin_amdgcn_mfma_f32_16x16x32_bf16(Al0, Bh[0][0], c0, 0, 0, 0);
      c0 = __builtin_amdgcn_mfma_f32_16x16x32_bf16(Ah1, Bh[0][1], c0, 0, 0, 0);
      c0 = __builtin_amdgcn_mfma_f32_16x16x32_bf16(Ah1, Bl[0][1], c0, 0, 0, 0);
      c0 = __builtin_amdgcn_mfma_f32_16x16x32_bf16(Al1, Bh[0][1], c0, 0, 0, 0);
      c1 = __builtin_amdgcn_mfma_f32_16x16x32_bf16(Ah0, Bh[1][0], c1, 0, 0, 0);
      c1 = __builtin_amdgcn_mfma_f32_16x16x32_bf16(Ah0, Bl[1][0], c1, 0, 0, 0);
      c1 = __builtin_amdgcn_mfma_f32_16x16x32_bf16(Al0, Bh[1][0], c1, 0, 0, 0);
      c1 = __builtin_amdgcn_mfma_f32_16x16x32_bf16(Ah1, Bh[1][1], c1, 0, 0, 0);
      c1 = __builtin_amdgcn_mfma_f32_16x16x32_bf16(Ah1, Bl[1][1], c1, 0, 0, 0);
      c1 = __builtin_amdgcn_mfma_f32_16x16x32_bf16(Al1, Bh[1][1], c1, 0, 0, 0);
      #pragma unroll
      for (int i2 = 0; i2 < 4; ++i2) {
        int m = lh * 4 + i2, tl = m & 7, blw = bp * 2 + (m >> 3);
        pbuf[psel][tl][blw][lm] = c0[i2] + bias[0];
        if (lm < 8) pbuf[psel][tl][blw][16 + lm] = c1[i2] + bias[1];
      }
    }
  };

  float g[8];
  #pragma unroll
  for (int k = 0; k < 8; ++k) g[k] = 0.0f;

  // ---- prologue: proj chunk 0 ----
  load_chunk(0);
  proj(0);

  #pragma unroll 1
  for (int c = 0; c < NCH; ++c) {
    const int ps = c & 1;
    // bulk gate preload for scan(c) (24 ds_read, off the per-step critical path)
    float sr[TC], sz[TC], sn[TC];
    {
      const float* pp = &pbuf[ps][0][bl][0];
      #pragma unroll
      for (int t = 0; t < TC; ++t) {
        sr[t] = pp[t * (8 * Gn) + j];
        sz[t] = pp[t * (8 * Gn) + 8 + j];
        sn[t] = pp[t * (8 * Gn) + 16 + j];
      }
    }
    // issue next chunk's global loads; scan hides the latency
    if (c + 1 < NCH) load_chunk(c + 1);

    // ---- scan 8 steps: Pade activations, DPP butterfly ----
    #pragma unroll
    for (int t = 0; t < TC; ++t) {
      float ghr = bhr, ghz = bhz, ghn = bhn;
      const int ko[8] = {0, 1, 2, 3, 7, 6, 5, 4};  // deepest-DPP value last
      #pragma unroll
      for (int q = 0; q < 8; ++q) {
        int k = ko[q];
        ghr = fmaf(whr[k], g[k], ghr);
        ghz = fmaf(whz[k], g[k], ghz);
        ghn = fmaf(whn[k], g[k], ghn);
      }
      float r  = fmaf(0.5f, pade_tanh(sr[t] + ghr), 0.5f);   // sigma at half-scale
      float z  = fmaf(0.5f, pade_tanh(sz[t] + ghz), 0.5f);
      float nv = pade_tanh(fmaf(r, ghn, sn[t]));
      float hj = fmaf(z, g[0] - nv, nv);   // (1-z)*n + z*h
      g[0] = hj;
      g[1] = xf1(g[0]); g[2] = xf2(g[0]); g[3] = xf2(g[1]);
      g[7] = xf7(g[0]); g[6] = xf7(g[1]); g[5] = xf7(g[2]); g[4] = xf7(g[3]);
    }

    // ---- proj chunk c+1 into the other pbuf ----
    if (c + 1 < NCH) proj(ps ^ 1);
  }

  if (j == 0) {
    float o = bd;
    #pragma unroll
    for (int k = 0; k < 8; ++k) o = fmaf(wd[k], g[k], o);  // lane j=0: g[k]=h[k]
    out[b0 + bl] = o;
  }
}

extern "C" void kernel_launch(void* const* d_in, const int* in_sizes, int n_in,
                              void* d_out, int out_size, void* d_ws, size_t ws_size,
                              hipStream_t stream) {
  const float* x     = (const float*)d_in[0];
  const float* w_ih  = (const float*)d_in[1];
  const float* w_hh  = (const float*)d_in[2];
  const float* b_ih  = (const float*)d_in[3];
  const float* b_hh  = (const float*)d_in[4];
  const float* w_dec = (const float*)d_in[5];
  const float* b_dec = (const float*)d_in[6];
  float* out = (float*)d_out;
  (void)d_ws; (void)ws_size;

  k_fused<<<dim3(Bn / 8), dim3(64), 0, stream>>>(x, w_ih, w_hh, b_ih, b_hh,
                                                 w_dec, b_dec, out);
}